// Round 1
// baseline (1170.233 us; speedup 1.0000x reference)
//
#include <hip/hip_runtime.h>
#include <hip/hip_bf16.h>

// QwenMoe: T=1024 H=2048 I=1408 E=60 SI=5632 topk=4, all inputs fp32, out fp32.
// Strategy: fp32 router (exact top-k), sparse grouped bf16-MFMA GEMMs for experts.

typedef float  f32x4  __attribute__((ext_vector_type(4)));
typedef short  bf16x8 __attribute__((ext_vector_type(8)));
typedef unsigned short u16;
typedef unsigned int   u32;

constexpr int TT = 1024, HD = 2048, ID = 1408, NE = 60, SID = 5632, KTOP = 4;

__device__ __forceinline__ u16 f2bf(float f) {
    union { float f; u32 u; } v; v.f = f;
    u32 r = v.u + 0x7FFFu + ((v.u >> 16) & 1u);   // RNE
    return (u16)(r >> 16);
}
__device__ __forceinline__ float bf2f(u16 b) {
    union { float f; u32 u; } v; v.u = ((u32)b) << 16; return v.f;
}
__device__ __forceinline__ uint4 pack8(float4 a, float4 b) {
    uint4 r;
    r.x = (u32)f2bf(a.x) | ((u32)f2bf(a.y) << 16);
    r.y = (u32)f2bf(a.z) | ((u32)f2bf(a.w) << 16);
    r.z = (u32)f2bf(b.x) | ((u32)f2bf(b.y) << 16);
    r.w = (u32)f2bf(b.z) | ((u32)f2bf(b.w) << 16);
    return r;
}
// LDS chunk swizzle: 4 chunks of 8 bf16 per 32-elem row; spreads b128 reads to ~2-way.
__device__ __forceinline__ int swz(int row, int c) { return c ^ ((row ^ (row >> 2)) & 3); }

// ---------------- router: logits, softmax, top-4, counts, shared sigmoid gate ----------
__global__ __launch_bounds__(64) void router_k(
    const float* __restrict__ x, const float* __restrict__ rw,
    const float* __restrict__ sgw,
    float* __restrict__ topk_p, int* __restrict__ topk_i,
    int* __restrict__ cnt, float* __restrict__ sgate)
{
    const int t = blockIdx.x, l = threadIdx.x;
    const float4* xr = ((const float4*)(x + (size_t)t * HD)) + l * 8;
    float4 xa[8];
    #pragma unroll
    for (int i = 0; i < 8; i++) xa[i] = xr[i];

    float le = 0.f;
    for (int e = 0; e < NE; e++) {
        const float4* wr = ((const float4*)(rw + (size_t)e * HD)) + l * 8;
        float a = 0.f;
        #pragma unroll
        for (int i = 0; i < 8; i++) {
            float4 wv = wr[i];
            a += xa[i].x * wv.x + xa[i].y * wv.y + xa[i].z * wv.z + xa[i].w * wv.w;
        }
        #pragma unroll
        for (int s = 32; s; s >>= 1) a += __shfl_xor(a, s);
        if (l == e) le = a;
    }
    {   // shared expert sigmoid gate logit
        const float4* wr = ((const float4*)sgw) + l * 8;
        float a = 0.f;
        #pragma unroll
        for (int i = 0; i < 8; i++) {
            float4 wv = wr[i];
            a += xa[i].x * wv.x + xa[i].y * wv.y + xa[i].z * wv.z + xa[i].w * wv.w;
        }
        #pragma unroll
        for (int s = 32; s; s >>= 1) a += __shfl_xor(a, s);
        if (l == 0) sgate[t] = 1.f / (1.f + __expf(-a));
    }
    // softmax over 60 experts (lane e holds logit e)
    float mv = (l < NE) ? le : -3.4e38f;
    #pragma unroll
    for (int s = 32; s; s >>= 1) mv = fmaxf(mv, __shfl_xor(mv, s));
    float p = (l < NE) ? __expf(le - mv) : 0.f;
    float ss = p;
    #pragma unroll
    for (int s = 32; s; s >>= 1) ss += __shfl_xor(ss, s);
    p /= ss;
    // iterative top-4 (tie-break: lowest index, matching lax.top_k)
    float pv = (l < NE) ? p : -1.f;
    int   pi = l;
    float kp = 0.f; int ki = 0;
    for (int k = 0; k < KTOP; k++) {
        float bv = pv; int bi = pi;
        #pragma unroll
        for (int s = 32; s; s >>= 1) {
            float ov = __shfl_xor(bv, s); int oi = __shfl_xor(bi, s);
            if (ov > bv || (ov == bv && oi < bi)) { bv = ov; bi = oi; }
        }
        if (l == k) { kp = bv; ki = bi; }
        if (pi == bi) pv = -1.f;
    }
    if (l < KTOP) {
        topk_p[t * KTOP + l] = kp;
        topk_i[t * KTOP + l] = ki;
        atomicAdd(&cnt[ki], 1);
    }
}

__global__ __launch_bounds__(64) void prefix_k(const int* __restrict__ cnt, int* __restrict__ base)
{
    int l = threadIdx.x;
    if (l < NE) {
        int s = 0;
        for (int j = 0; j < l; j++) s += cnt[j];
        base[l] = s;
    }
}

__global__ __launch_bounds__(256) void scatter_k(
    const float* __restrict__ topk_p, const int* __restrict__ topk_i,
    const int* __restrict__ base, int* __restrict__ fill,
    int* __restrict__ slot_tok, float* __restrict__ slot_wt)
{
    int t = blockIdx.x * blockDim.x + threadIdx.x;
    if (t >= TT) return;
    for (int k = 0; k < KTOP; k++) {
        int e = topk_i[t * KTOP + k];
        int pos = atomicAdd(&fill[e], 1);
        int s = base[e] + pos;
        slot_tok[s] = t;
        slot_wt[s]  = topk_p[t * KTOP + k];
    }
}

// ---------------- generic 128x128x32 bf16-MFMA GEMM, A[M][K] * B[N][K]^T ---------------
// MODE 0: C_bf16 = acc                       (gate pre-activations)
// MODE 1: C_bf16 = silu(G)*acc*scale         (up proj, fused SwiGLU + combine weight)
// MODE 2: out_f32 = sgate[row]*acc           (shared down, full overwrite)
// MODE 3: atomicAdd(out[slot_tok[row]], acc) (routed down, accumulate)
template<int MODE, bool ABF16, bool GROUPED>
__global__ __launch_bounds__(256) void gemm_k(
    const float* __restrict__ Af32, const u16* __restrict__ Abf16,
    const float* __restrict__ Bbase, size_t bStride,
    u16* __restrict__ Cbf, const u16* __restrict__ Gbf,
    float* __restrict__ outF,
    const int* __restrict__ slot_tok, const float* __restrict__ slot_wt,
    const float* __restrict__ sgate,
    const int* __restrict__ cnt, const int* __restrict__ basearr,
    int K, int N, int TR)
{
    __shared__ u16 Asl[128 * 32];
    __shared__ u16 Bsl[128 * 32];

    const int tid  = threadIdx.x;
    const int e    = GROUPED ? blockIdx.z : 0;
    const int mcnt = GROUPED ? cnt[e] : TR;
    const int mbase = GROUPED ? basearr[e] : 0;
    const float* Bp = Bbase + (size_t)e * bStride;

    const int srow  = tid >> 1;          // staging row 0..127 (tile-local)
    const int skoff = (tid & 1) * 16;    // staging k offset (0 or 16)
    const int w = tid >> 6, l = tid & 63;
    const int wm0 = (w >> 1) * 64, wn0 = (w & 1) * 64;
    const int lm = l & 15, lk = l >> 4;
    const int brow = blockIdx.x * 128 + srow;
    const float* browp = Bp + (size_t)brow * K + skoff;

    for (int mt = blockIdx.y; mt * 128 < mcnt; mt += gridDim.y) {
        const bool avalid = (mt * 128 + srow) < mcnt;
        const int  slotr  = mbase + mt * 128 + srow;
        size_t agrow;
        if constexpr (ABF16)        agrow = (size_t)slotr;
        else if constexpr (GROUPED) agrow = avalid ? (size_t)slot_tok[slotr] : 0;
        else                        agrow = (size_t)slotr;
        const float* arow_f = ABF16 ? nullptr : (Af32 + agrow * (size_t)K + skoff);
        const u16*   arow_b = ABF16 ? (Abf16 + agrow * (size_t)K + skoff) : nullptr;

        f32x4 acc[4][4];
        #pragma unroll
        for (int mf = 0; mf < 4; mf++)
            #pragma unroll
            for (int nf = 0; nf < 4; nf++)
                acc[mf][nf] = f32x4{0.f, 0.f, 0.f, 0.f};

        for (int kt = 0; kt < K; kt += 32) {
            uint4 aw0, aw1, bw0, bw1;
            if constexpr (ABF16) {
                if (avalid) {
                    const uint4* p = (const uint4*)(arow_b + kt);
                    aw0 = p[0]; aw1 = p[1];
                } else { aw0 = make_uint4(0,0,0,0); aw1 = make_uint4(0,0,0,0); }
            } else {
                float4 f0, f1, f2, f3;
                if (avalid) {
                    const float4* p = (const float4*)(arow_f + kt);
                    f0 = p[0]; f1 = p[1]; f2 = p[2]; f3 = p[3];
                } else {
                    f0 = f1 = f2 = f3 = make_float4(0.f, 0.f, 0.f, 0.f);
                }
                aw0 = pack8(f0, f1); aw1 = pack8(f2, f3);
            }
            {
                const float4* p = (const float4*)(browp + kt);
                float4 g0 = p[0], g1 = p[1], g2 = p[2], g3 = p[3];
                bw0 = pack8(g0, g1); bw1 = pack8(g2, g3);
            }
            __syncthreads();   // previous iteration's LDS reads complete
            const int c0 = skoff >> 3;  // 0 or 2
            *(uint4*)&Asl[srow * 32 + (swz(srow, c0    ) << 3)] = aw0;
            *(uint4*)&Asl[srow * 32 + (swz(srow, c0 + 1) << 3)] = aw1;
            *(uint4*)&Bsl[srow * 32 + (swz(srow, c0    ) << 3)] = bw0;
            *(uint4*)&Bsl[srow * 32 + (swz(srow, c0 + 1) << 3)] = bw1;
            __syncthreads();
            bf16x8 af[4], bf[4];
            #pragma unroll
            for (int mf = 0; mf < 4; mf++) {
                int r = wm0 + mf * 16 + lm;
                af[mf] = *(const bf16x8*)&Asl[r * 32 + (swz(r, lk) << 3)];
            }
            #pragma unroll
            for (int nf = 0; nf < 4; nf++) {
                int r = wn0 + nf * 16 + lm;
                bf[nf] = *(const bf16x8*)&Bsl[r * 32 + (swz(r, lk) << 3)];
            }
            #pragma unroll
            for (int mf = 0; mf < 4; mf++)
                #pragma unroll
                for (int nf = 0; nf < 4; nf++)
                    acc[mf][nf] = __builtin_amdgcn_mfma_f32_16x16x32_bf16(
                        af[mf], bf[nf], acc[mf][nf], 0, 0, 0);
        }

        // epilogue — D layout: col = lane&15, row = (lane>>4)*4 + reg  [m89/m91-verified]
        #pragma unroll
        for (int mf = 0; mf < 4; mf++) {
            #pragma unroll
            for (int j = 0; j < 4; j++) {
                int rl = wm0 + mf * 16 + lk * 4 + j;
                if (mt * 128 + rl < mcnt) {
                    size_t srowg = (size_t)(mbase + mt * 128 + rl);
                    float sc = 1.f;
                    if constexpr (MODE == 1) { if constexpr (GROUPED) sc = slot_wt[srowg]; }
                    int tok = 0;
                    if constexpr (MODE == 3) tok = slot_tok[srowg];
                    float gv = 0.f;
                    if constexpr (MODE == 2) gv = sgate[srowg];
                    #pragma unroll
                    for (int nf = 0; nf < 4; nf++) {
                        int col = blockIdx.x * 128 + wn0 + nf * 16 + lm;
                        float v = acc[mf][nf][j];
                        if constexpr (MODE == 0) {
                            Cbf[srowg * (size_t)N + col] = f2bf(v);
                        } else if constexpr (MODE == 1) {
                            float g  = bf2f(Gbf[srowg * (size_t)N + col]);
                            float sl = g / (1.f + __expf(-g));
                            Cbf[srowg * (size_t)N + col] = f2bf(sl * v * sc);
                        } else if constexpr (MODE == 2) {
                            outF[srowg * (size_t)N + col] = gv * v;
                        } else {
                            atomicAdd(&outF[(size_t)tok * (size_t)N + col], v);
                        }
                    }
                }
            }
        }
    }
}

extern "C" void kernel_launch(void* const* d_in, const int* in_sizes, int n_in,
                              void* d_out, int out_size, void* d_ws, size_t ws_size,
                              hipStream_t stream)
{
    const float* x      = (const float*)d_in[0];
    const float* rw     = (const float*)d_in[1];
    const float* w_gate = (const float*)d_in[2];
    const float* w_up   = (const float*)d_in[3];
    const float* w_down = (const float*)d_in[4];
    const float* sw_g   = (const float*)d_in[5];
    const float* sw_u   = (const float*)d_in[6];
    const float* sw_d   = (const float*)d_in[7];
    const float* sgw    = (const float*)d_in[8];
    float* out = (float*)d_out;

    char* ws = (char*)d_ws;
    int*   cnt      = (int*)(ws + 0);        // 60 ints
    int*   fill     = (int*)(ws + 256);      // 60 ints
    int*   basea    = (int*)(ws + 512);      // 60 ints
    float* sgate    = (float*)(ws + 768);    // 1024 f32
    float* topk_p   = (float*)(ws + 5120);   // 4096 f32
    int*   topk_i   = (int*)(ws + 21504);    // 4096 int
    int*   slot_tok = (int*)(ws + 37888);    // 4096 int
    float* slot_wt  = (float*)(ws + 54272);  // 4096 f32
    u16*   xg = (u16*)(ws + 71680);                    // [4096][1408] bf16
    u16*   h  = xg + (size_t)4096 * ID;                // [4096][1408] bf16
    u16*   sg = h  + (size_t)4096 * ID;                // [1024][5632] bf16
    u16*   hs = sg + (size_t)TT * SID;                 // [1024][5632] bf16

    hipMemsetAsync(ws, 0, 512, stream);  // zero cnt + fill

    router_k<<<TT, 64, 0, stream>>>(x, rw, sgw, topk_p, topk_i, cnt, sgate);
    prefix_k<<<1, 64, 0, stream>>>(cnt, basea);
    scatter_k<<<4, 256, 0, stream>>>(topk_p, topk_i, basea, fill, slot_tok, slot_wt);

    // routed gate: xg = X @ w_gate[e]^T   (K=H, N=I)
    gemm_k<0, false, true><<<dim3(ID / 128, 2, NE), 256, 0, stream>>>(
        x, nullptr, w_gate, (size_t)ID * HD, xg, nullptr, nullptr,
        slot_tok, slot_wt, sgate, cnt, basea, HD, ID, 0);
    // routed up fused SwiGLU: h = silu(xg) * (X @ w_up^T) * combine_w
    gemm_k<1, false, true><<<dim3(ID / 128, 2, NE), 256, 0, stream>>>(
        x, nullptr, w_up, (size_t)ID * HD, h, xg, nullptr,
        slot_tok, slot_wt, sgate, cnt, basea, HD, ID, 0);
    // shared gate: sg = X @ sw_gate^T    (K=H, N=SI)
    gemm_k<0, false, false><<<dim3(SID / 128, TT / 128, 1), 256, 0, stream>>>(
        x, nullptr, sw_g, 0, sg, nullptr, nullptr,
        nullptr, nullptr, nullptr, nullptr, nullptr, HD, SID, TT);
    // shared up fused SwiGLU: hs = silu(sg) * (X @ sw_up^T)
    gemm_k<1, false, false><<<dim3(SID / 128, TT / 128, 1), 256, 0, stream>>>(
        x, nullptr, sw_u, 0, hs, sg, nullptr,
        nullptr, nullptr, nullptr, nullptr, nullptr, HD, SID, TT);
    // shared down + sigmoid gate, overwrites out: out = sigmoid(z) * (hs @ sw_down^T)
    gemm_k<2, true, false><<<dim3(HD / 128, TT / 128, 1), 256, 0, stream>>>(
        nullptr, hs, sw_d, 0, nullptr, nullptr, out,
        nullptr, nullptr, sgate, nullptr, nullptr, SID, HD, TT);
    // routed down, accumulates: out[tok] += h @ w_down[e]^T
    gemm_k<3, true, true><<<dim3(HD / 128, 2, NE), 256, 0, stream>>>(
        nullptr, h, w_down, (size_t)HD * ID, nullptr, nullptr, out,
        slot_tok, slot_wt, sgate, cnt, basea, ID, HD, 0);
}